// Round 3
// baseline (48.202 us; speedup 1.0000x reference)
//
#include <hip/hip_runtime.h>
#include <math.h>

constexpr int IN_C = 31;
constexpr int TOT  = 44;
constexpr int HW   = 256 * 256;
constexpr int NPIX = 4 * HW;
constexpr float SMIN = 0.001f, SMAX = 1000.0f;
constexpr float PI_F = 3.14159265358979323846f;

typedef __attribute__((address_space(1))) const unsigned int g_u32;
typedef __attribute__((address_space(3))) unsigned int lds_u32;

// One thread per pixel, 256 threads/block = 4 waves.
// Per-wave 8KB LDS region serves double duty (wave-synchronous, no barriers):
//   1) async DMA staging of the wave's x-tile (64 px x 31 ch, global_load_lds,
//      zero VGPR cost, single vmcnt wait) -> GEMV reads from LDS.
//   2) two-phase staged flush of S for fully-coalesced global writes.
__global__ __launch_bounds__(256) void sepgpd_fused(
    const float* __restrict__ x,
    const float* __restrict__ Wenc,
    const float* __restrict__ benc,
    float* __restrict__ out)
{
    __shared__ float sbuf[4][2048];   // 32 KB: 4 waves x 8 KB

    const int tid  = threadIdx.x;
    const int lane = tid & 63;
    const int wid  = tid >> 6;
    const int pix  = blockIdx.x * 256 + tid;   // grid exactly covers NPIX
    const int b    = pix >> 16;                // HW = 65536
    const int hw   = pix & (HW - 1);

    const float* xb = x + (size_t)b * IN_C * HW + hw;
    float* wbuf = &sbuf[wid][0];

    // ---- async DMA: x tile -> LDS (31 insts, all in flight, no VGPRs) ----
    // DMA writes wave-uniform base + lane*4; channel c row at wbuf + c*64.
#pragma unroll
    for (int c = 0; c < IN_C; ++c) {
        __builtin_amdgcn_global_load_lds(
            (g_u32*)(xb + (size_t)c * HW),
            (lds_u32*)(wbuf + c * 64),
            4, 0, 0);
    }
    asm volatile("s_waitcnt vmcnt(0)" ::: "memory");

    // ---- 44x31 GEMV from LDS (weights via scalar cache: uniform indices) ----
    float acc[TOT];
#pragma unroll
    for (int o = 0; o < TOT; ++o) acc[o] = benc[o];

#pragma unroll
    for (int c = 0; c < IN_C; ++c) {
        const float xc = wbuf[c * 64 + lane];   // ds_read_b32, conflict-free
#pragma unroll
        for (int o = 0; o < TOT; ++o)
            acc[o] = fmaf(xc, Wenc[o * IN_C + c], acc[o]);
    }

    // ---- m: first 8 channels, per-pixel contiguous ----
    float4* mp = reinterpret_cast<float4*>(out + (size_t)pix * 8);
    mp[0] = make_float4(acc[0], acc[1], acc[2], acc[3]);
    mp[1] = make_float4(acc[4], acc[5], acc[6], acc[7]);

    // ---- sqrt of scales: S = (sqrtD R)^T (sqrtD R) is exactly symmetric ----
    float sq[8];
#pragma unroll
    for (int j = 0; j < 8; ++j) {
        const float sig = 1.0f / (1.0f + __expf(-acc[8 + j]));
        const float s   = SMIN + (SMAX - SMIN) * sig;
        sq[j] = sqrtf(s);
    }

    // ---- R: product of Givens rotations applied to identity ----
    float R[8][8];
#pragma unroll
    for (int i = 0; i < 8; ++i)
#pragma unroll
        for (int k = 0; k < 8; ++k) R[i][k] = (i == k) ? 1.0f : 0.0f;

    int cc = 0;
#pragma unroll
    for (int i = 0; i < 7; ++i) {
#pragma unroll
        for (int j = i + 1; j < 8; ++j) {
            const float wv = acc[16 + cc];
            const float th = 1.0f - 2.0f / (__expf(2.0f * wv) + 1.0f);
            const float a  = PI_F * th;
            const float cs = __cosf(a);
            const float ss = __sinf(a);
#pragma unroll
            for (int r = 0; r < 8; ++r) {
                const float ri = R[r][i];
                const float rj = R[r][j];
                R[r][i] = fmaf(ri, cs, rj * ss);
                R[r][j] = fmaf(rj, cs, -(ri * ss));
            }
            ++cc;
        }
    }

    // scale row j by sqrt(s_j)
#pragma unroll
    for (int j = 0; j < 8; ++j)
#pragma unroll
        for (int k = 0; k < 8; ++k) R[j][k] *= sq[j];

    // ---- S[i][k] = dot(col_i, col_k), symmetric ----
    float S[8][8];
#pragma unroll
    for (int i = 0; i < 8; ++i) {
#pragma unroll
        for (int k = i; k < 8; ++k) {
            float d = 0.0f;
#pragma unroll
            for (int j = 0; j < 8; ++j) d = fmaf(R[j][i], R[j][k], d);
            S[i][k] = d;
            S[k][i] = d;
        }
    }

    // ---- two-phase staged flush of S (reuses the x-staging LDS region) ----
    // Wave-synchronous: all lanes finished reading x before staging S.
    float4* wbuf4 = reinterpret_cast<float4*>(wbuf);
    float4* S4 = reinterpret_cast<float4*>(out + (size_t)NPIX * 8);
    const size_t pixbase4 = (size_t)(blockIdx.x * 256 + wid * 64) * 16; // float4s

#pragma unroll
    for (int p = 0; p < 2; ++p) {
        // stage rows 4p .. 4p+3 (32 floats/pixel), swizzle v ^ (lane&7)
#pragma unroll
        for (int r = 0; r < 4; ++r) {
            const int i  = 4 * p + r;
            const int v0 = r * 2;
            const int v1 = v0 + 1;
            wbuf4[lane * 8 + (v0 ^ (lane & 7))] =
                make_float4(S[i][0], S[i][1], S[i][2], S[i][3]);
            wbuf4[lane * 8 + (v1 ^ (lane & 7))] =
                make_float4(S[i][4], S[i][5], S[i][6], S[i][7]);
        }
        // coalesced flush: 8 iters x 64 lanes x 16B = 8KB contiguous
#pragma unroll
        for (int k = 0; k < 8; ++k) {
            const int t  = k * 64 + lane;
            const int pl = t >> 3;           // local pixel 0..63
            const int v  = t & 7;            // float4 index within half
            S4[pixbase4 + (size_t)pl * 16 + p * 8 + v] =
                wbuf4[pl * 8 + (v ^ (pl & 7))];
        }
    }
}

extern "C" void kernel_launch(void* const* d_in, const int* in_sizes, int n_in,
                              void* d_out, int out_size, void* d_ws, size_t ws_size,
                              hipStream_t stream)
{
    const float* x    = (const float*)d_in[0];
    const float* Wenc = (const float*)d_in[1];
    const float* benc = (const float*)d_in[2];
    float* out        = (float*)d_out;

    dim3 grid(NPIX / 256), block(256);
    sepgpd_fused<<<grid, block, 0, stream>>>(x, Wenc, benc, out);
}

// Round 4
// 41.296 us; speedup vs baseline: 1.1672x; 1.1672x over previous
//
#include <hip/hip_runtime.h>
#include <math.h>

constexpr int IN_C = 31;
constexpr int TOT  = 44;
constexpr int HW   = 256 * 256;
constexpr int NPIX = 4 * HW;
constexpr float SMIN = 0.001f, SMAX = 1000.0f;
constexpr float PI_F = 3.14159265358979323846f;

// One thread per pixel, 256 threads/block = 4 waves.
// GEMV: x in 31 VGPRs (loaded once, coalesced); weight rows read CONTIGUOUSLY
// (o outer, c inner) so the compiler batches them into s_load_dwordx8/x16
// instead of ~1364 strided s_load_dword (the R1-R3 serialization).
// S flushed in two wave-synchronous phases through 8KB/wave LDS (32KB/block).
__global__ __launch_bounds__(256) void sepgpd_fused(
    const float* __restrict__ x,
    const float* __restrict__ Wenc,
    const float* __restrict__ benc,
    float* __restrict__ out)
{
    __shared__ float sbuf[4][2048];   // 32 KB: 4 waves x 8 KB

    const int tid  = threadIdx.x;
    const int lane = tid & 63;
    const int wid  = tid >> 6;
    const int pix  = blockIdx.x * 256 + tid;   // grid exactly covers NPIX
    const int b    = pix >> 16;                // HW = 65536
    const int hw   = pix & (HW - 1);

    const float* xb = x + (size_t)b * IN_C * HW + hw;

    // ---- x into registers: 31 coalesced loads, all in flight ----
    float xv[IN_C];
#pragma unroll
    for (int c = 0; c < IN_C; ++c) xv[c] = xb[(size_t)c * HW];

    // ---- 44x31 GEMV, contiguous weight rows (scalar-batched) ----
    float acc[TOT];
#pragma unroll
    for (int o = 0; o < TOT; ++o) {
        float a = benc[o];
#pragma unroll
        for (int c = 0; c < IN_C; ++c)
            a = fmaf(xv[c], Wenc[o * IN_C + c], a);
        acc[o] = a;
    }

    // ---- m: first 8 channels, per-pixel contiguous (coalesced 32B/lane) ----
    float4* mp = reinterpret_cast<float4*>(out + (size_t)pix * 8);
    mp[0] = make_float4(acc[0], acc[1], acc[2], acc[3]);
    mp[1] = make_float4(acc[4], acc[5], acc[6], acc[7]);

    // ---- sqrt of scales: S = (sqrtD R)^T (sqrtD R) is exactly symmetric ----
    float sq[8];
#pragma unroll
    for (int j = 0; j < 8; ++j) {
        const float sig = 1.0f / (1.0f + __expf(-acc[8 + j]));
        const float s   = SMIN + (SMAX - SMIN) * sig;
        sq[j] = sqrtf(s);
    }

    // ---- R: product of Givens rotations applied to identity ----
    float R[8][8];
#pragma unroll
    for (int i = 0; i < 8; ++i)
#pragma unroll
        for (int k = 0; k < 8; ++k) R[i][k] = (i == k) ? 1.0f : 0.0f;

    int cc = 0;
#pragma unroll
    for (int i = 0; i < 7; ++i) {
#pragma unroll
        for (int j = i + 1; j < 8; ++j) {
            const float wv = acc[16 + cc];
            const float th = 1.0f - 2.0f / (__expf(2.0f * wv) + 1.0f);
            const float a  = PI_F * th;
            const float cs = __cosf(a);
            const float ss = __sinf(a);
#pragma unroll
            for (int r = 0; r < 8; ++r) {
                const float ri = R[r][i];
                const float rj = R[r][j];
                R[r][i] = fmaf(ri, cs, rj * ss);
                R[r][j] = fmaf(rj, cs, -(ri * ss));
            }
            ++cc;
        }
    }

    // scale row j by sqrt(s_j)
#pragma unroll
    for (int j = 0; j < 8; ++j)
#pragma unroll
        for (int k = 0; k < 8; ++k) R[j][k] *= sq[j];

    // ---- S[i][k] = dot(col_i, col_k), symmetric ----
    float S[8][8];
#pragma unroll
    for (int i = 0; i < 8; ++i) {
#pragma unroll
        for (int k = i; k < 8; ++k) {
            float d = 0.0f;
#pragma unroll
            for (int j = 0; j < 8; ++j) d = fmaf(R[j][i], R[j][k], d);
            S[i][k] = d;
            S[k][i] = d;
        }
    }

    // ---- two-phase staged flush of S (wave-synchronous, buffer reused) ----
    float* wbuf = &sbuf[wid][0];
    float4* wbuf4 = reinterpret_cast<float4*>(wbuf);
    float4* S4 = reinterpret_cast<float4*>(out + (size_t)NPIX * 8);
    const size_t pixbase4 = (size_t)(blockIdx.x * 256 + wid * 64) * 16; // float4s

#pragma unroll
    for (int p = 0; p < 2; ++p) {
        // stage rows 4p .. 4p+3 (32 floats/pixel), swizzle v ^ (lane&7)
#pragma unroll
        for (int r = 0; r < 4; ++r) {
            const int i  = 4 * p + r;
            const int v0 = r * 2;
            const int v1 = v0 + 1;
            wbuf4[lane * 8 + (v0 ^ (lane & 7))] =
                make_float4(S[i][0], S[i][1], S[i][2], S[i][3]);
            wbuf4[lane * 8 + (v1 ^ (lane & 7))] =
                make_float4(S[i][4], S[i][5], S[i][6], S[i][7]);
        }
        // coalesced flush: 8 iters x 64 lanes x 16B = 8KB contiguous
#pragma unroll
        for (int k = 0; k < 8; ++k) {
            const int t  = k * 64 + lane;
            const int pl = t >> 3;           // local pixel 0..63
            const int v  = t & 7;            // float4 index within half
            S4[pixbase4 + (size_t)pl * 16 + p * 8 + v] =
                wbuf4[pl * 8 + (v ^ (pl & 7))];
        }
    }
}

extern "C" void kernel_launch(void* const* d_in, const int* in_sizes, int n_in,
                              void* d_out, int out_size, void* d_ws, size_t ws_size,
                              hipStream_t stream)
{
    const float* x    = (const float*)d_in[0];
    const float* Wenc = (const float*)d_in[1];
    const float* benc = (const float*)d_in[2];
    float* out        = (float*)d_out;

    dim3 grid(NPIX / 256), block(256);
    sepgpd_fused<<<grid, block, 0, stream>>>(x, Wenc, benc, out);
}